// Round 2
// baseline (789.933 us; speedup 1.0000x reference)
//
#include <hip/hip_runtime.h>
#include <hip/hip_bf16.h>

typedef __bf16  bf16x8 __attribute__((ext_vector_type(8)));
typedef float   f32x4  __attribute__((ext_vector_type(4)));

// global->LDS async, 16B/lane. _C: fully cached (immutable X stream).
// _H: sc0 = bypass L1, allocate L2 (h panels; freshness via 12-deep slot
// rotation + aligned fence every 8 phases -- proven R7).
#define GLOAD16_C(gptr, lptr) \
  __builtin_amdgcn_global_load_lds((const __attribute__((address_space(1))) void*)(gptr), \
                                   (__attribute__((address_space(3))) void*)(lptr), 16, 0, 0)
#define GLOAD16_H(gptr, lptr) \
  __builtin_amdgcn_global_load_lds((const __attribute__((address_space(1))) void*)(gptr), \
                                   (__attribute__((address_space(3))) void*)(lptr), 16, 0, 0x1)

#define WAIT_VM12  asm volatile("s_waitcnt vmcnt(12)" ::: "memory")
#define WAIT_VM10  asm volatile("s_waitcnt vmcnt(10)" ::: "memory")
#define WAIT_VM8   asm volatile("s_waitcnt vmcnt(8)"  ::: "memory")
#define WAIT_VM6   asm volatile("s_waitcnt vmcnt(6)"  ::: "memory")
#define WAIT_VM4   asm volatile("s_waitcnt vmcnt(4)"  ::: "memory")
#define WAIT_VM2   asm volatile("s_waitcnt vmcnt(2)"  ::: "memory")
#define WAIT_VM0   asm volatile("s_waitcnt vmcnt(0)"  ::: "memory")

__device__ __forceinline__ void wait_vm_chunks(int n) {   // n chunks (2 vm each) may stay outstanding
  if      (n <= 0) WAIT_VM0;
  else if (n == 1) WAIT_VM2;
  else if (n == 2) WAIT_VM4;
  else if (n == 3) WAIT_VM6;
  else if (n == 4) WAIT_VM8;
  else if (n == 5) WAIT_VM10;
  else             WAIT_VM12;
}
__device__ __forceinline__ void wait_lgkm_n(int n) {
  if      (n <= 0) asm volatile("s_waitcnt lgkmcnt(0)" ::: "memory");
  else if (n <= 2) asm volatile("s_waitcnt lgkmcnt(2)" ::: "memory");
  else             asm volatile("s_waitcnt lgkmcnt(6)" ::: "memory");
}

__device__ __forceinline__ float sigm(float x)  { return 1.0f / (1.0f + __expf(-x)); }
__device__ __forceinline__ float tanhp(float x) { return 2.0f / (1.0f + __expf(-2.0f * x)) - 1.0f; }

// LLC-coherent scalar load / stores (bypass L1/L2)
__device__ __forceinline__ unsigned int coh_load(const unsigned int* p) {
  unsigned int v;
  asm volatile("global_load_dword %0, %1, off sc0 sc1\n\ts_waitcnt vmcnt(0)"
               : "=v"(v) : "v"(p) : "memory");
  return v;
}
__device__ __forceinline__ int coh_load_i(const int* p) {
  int v;
  asm volatile("global_load_dword %0, %1, off sc0 sc1\n\ts_waitcnt vmcnt(0)"
               : "=v"(v) : "v"(p) : "memory");
  return v;
}
__device__ __forceinline__ void coh_store16(void* p, bf16x8 v) {
  f32x4 f = *(f32x4*)&v;
  asm volatile("global_store_dwordx4 %0, %1, off sc0 sc1" :: "v"(p), "v"(f) : "memory");
}
__device__ __forceinline__ void flag_store(int* fp, int v) {
  asm volatile("global_store_dword %0, %1, off sc0 sc1" :: "v"(fp), "v"(v) : "memory");
}

#define TSTEPS 80
#define BATCH  512
#define EDIM   256
#define HDIM   512
#define K2     1024
#define K1     768
#define NCH    16           // B K-chunks in registers (256 VGPR; 1 wave/SIMD -> budget 512)
#define D_SLOTS 12
#define SLOT_BYTES 524544   // 512 KB + 256 B guard
// LDS: BsL (<=16 chunks * 4KB = 64KB) | ring (8 * 8KB = 64KB) | epi (128 x 24 bf16)
#define RING_OFF 65536
#define EPI_OFF  131072
#define EPI_STR  24
#define LDS_BYTES 137216

struct Params {
  const __hip_bfloat16* Wz1t;   // [2048][768]  bf16, [N'][K], K-order [W1|U1] (x first)
  const __hip_bfloat16* Wz2t;   // [2048][1024]             K-order [W2|U2] (h1 first)
  const float* bz1;             // [2048] permuted
  const float* bz2;
  const __hip_bfloat16* Xall;   // [80][512][256] bf16
  char* h1base;                 // 12 slots, SLOT_BYTES stride
  char* h2base;                 // 12 slots
  int* flags;                   // 256 entries, 16B stride: z1 at idx, z2 at 128+idx
  const float* Wfc; const float* bfc;
  float* out;
};

// ---------------- prep kernels ----------------
// permuted column: n' = ntile*64 + gate*16 + u  (ntile = j>>4, u = j&15)
// K-order: the TIGHT-gated operand goes LAST:
//   Wz1t: k<256 -> W1[k] (x),  k>=256 -> U1[k-256] (h1[s-1], peer-gated)
//   Wz2t: k<512 -> W2[k] (h1), k>=512 -> U2[k-512] (h2[s-1], peer-gated)

__global__ __launch_bounds__(256) void prep_weights(
    const float* __restrict__ W1, const float* __restrict__ U1, const float* __restrict__ b1,
    const float* __restrict__ W2, const float* __restrict__ U2, const float* __restrict__ b2,
    __hip_bfloat16* __restrict__ Wz1t, __hip_bfloat16* __restrict__ Wz2t,
    float* __restrict__ bz1, float* __restrict__ bz2) {
  long idx = (long)blockIdx.x * 256 + threadIdx.x;
  const long n1 = 2048L * K1, n2 = 2048L * K2;
  if (idx < n1) {
    int n = (int)(idx / K1), k = (int)(idx % K1);
    int col = ((n >> 4) & 3) * 512 + (n >> 6) * 16 + (n & 15);
    float v = (k < 256) ? W1[(size_t)k * 2048 + col] : U1[(size_t)(k - 256) * 2048 + col];
    Wz1t[idx] = __float2bfloat16(v);
  } else if (idx < n1 + n2) {
    long r = idx - n1;
    int n = (int)(r / K2), k = (int)(r % K2);
    int col = ((n >> 4) & 3) * 512 + (n >> 6) * 16 + (n & 15);
    float v = (k < 512) ? W2[(size_t)k * 2048 + col] : U2[(size_t)(k - 512) * 2048 + col];
    Wz2t[r] = __float2bfloat16(v);
  } else if (idx < n1 + n2 + 2048) {
    int n = (int)(idx - (n1 + n2));
    bz1[n] = b1[((n >> 4) & 3) * 512 + (n >> 6) * 16 + (n & 15)];
  } else if (idx < n1 + n2 + 4096) {
    int n = (int)(idx - (n1 + n2 + 2048));
    bz2[n] = b2[((n >> 4) & 3) * 512 + (n >> 6) * 16 + (n & 15)];
  }
}

__global__ __launch_bounds__(256) void prep_gather(
    const int* __restrict__ tokens, const float* __restrict__ emb,
    __hip_bfloat16* __restrict__ Xall, float4* __restrict__ zp, int zn) {
  int idx = blockIdx.x * 256 + threadIdx.x;
  if (idx < zn) zp[idx] = make_float4(0.f, 0.f, 0.f, 0.f);   // zero state+flags
  int e  = (idx & 63) * 4;
  int rb = idx >> 6;            // t*512 + b
  int t  = rb >> 9;
  int b  = rb & 511;
  int tok = tokens[b * TSTEPS + t];
  const float4 v = *(const float4*)&emb[(size_t)tok * EDIM + e];
  __hip_bfloat16* o = Xall + (size_t)rb * EDIM + e;
  o[0] = __float2bfloat16(v.x); o[1] = __float2bfloat16(v.y);
  o[2] = __float2bfloat16(v.z); o[3] = __float2bfloat16(v.w);
}

// ---------------- main kernel ----------------
// 256 blocks x 256 threads, 1 block/CU (1 wave/SIMD -> latency hidden by ILP).
// R8 schedule: BOTH gates observed in ONE poll call at the top of the step
// (one LLC round instead of two), then part A + part B run as a SINGLE merged
// K-stream over the 8-slot ring (no second fill bubble, no mid-step barrier).
// Ring lookahead deepened 6 -> 7 (slot of chunk kc-1 is provably read-complete
// when stage(kc+7) is issued). z1 pre-stages its immutable X chunks BEFORE the
// gate so X latency hides under the gate wait. Epilogue LDS transpose is
// wave-local (wave w touches only rows 32w..32w+31), so its first barrier is
// replaced by lgkmcnt(0). Coherence scheme unchanged from R7 (12-slot
// rotation, write-through sc0sc1 stores, agent-acquire fence every 8 phases,
// now before ALL coherent loads of the phase -- strictly more conservative).

__device__ __forceinline__ void gate_wave(const int* flags, int base1, int t1,
                                          int base2, int t2, int lane) {
  const int idx = lane & 31;
  const int* fp = flags + (((lane < 32) ? base1 : base2) + idx) * 4;   // 16B stride
  const int tgt = (lane < 32) ? t1 : t2;
  for (;;) {
    int v = coh_load_i(fp);
    if (__ballot(v >= tgt) == ~0ull) break;
    __builtin_amdgcn_s_sleep(2);
  }
}

// stage one 8KB K-chunk (per wave: its own 32-row quarter, 2 x 1KB loads).
// Chunks < SPLIT come from Aa (stride SA, cached iff !COHA); >= SPLIT from Ab
// (stride SB, always coherent). kc is compile-time at every call site.
template<int SPLIT, int SA, int SB, bool COHA>
__device__ __forceinline__ void stage_chunk(int kc,
    const __hip_bfloat16* __restrict__ Aa, const __hip_bfloat16* __restrict__ Ab,
    int m0, int w, int lane, __hip_bfloat16* __restrict__ ring) {
#pragma unroll
  for (int it = 0; it < 2; ++it) {
    const int gbase = w * 128 + it * 64;
    const int g   = gbase + lane;
    const int row = g >> 2;
    const int gc  = (g & 3) ^ ((row >> 1) & 3);       // XOR swizzle (pre-swizzled source)
    __hip_bfloat16* lp = ring + (kc & 7) * 4096 + gbase * 8;
    if (kc < SPLIT) {
      const __hip_bfloat16* gp = Aa + (size_t)(m0 + row) * SA + kc * 32 + gc * 8;
      if (COHA) { GLOAD16_H(gp, lp); } else { GLOAD16_C(gp, lp); }
    } else {
      const __hip_bfloat16* gp = Ab + (size_t)(m0 + row) * SB + (kc - SPLIT) * 32 + gc * 8;
      GLOAD16_H(gp, lp);
    }
  }
}

// merged K-loop: chunks 0..LEN-1, fill of chunks 0..6 already issued by caller.
// Steady state: stage(kc+7) -> 7 chunks in flight, wait allows 5 outstanding
// (chunk kc+1 resident). Slot (kc+7)&7 == (kc-1)&7: chunk kc-1's ds_reads
// retired at the previous iteration's lgkm wait -> overwrite safe.
template<int LEN, int SPLIT, int SA, int SB, bool COHA>
__device__ __forceinline__ void run_loop(
    const __hip_bfloat16* __restrict__ Aa, const __hip_bfloat16* __restrict__ Ab,
    int m0, int w, int lane,
    __hip_bfloat16* __restrict__ ring, const __hip_bfloat16* __restrict__ BsL,
    const bf16x8 (&breg)[NCH][4], const int (&aoff)[2], const int (&boff)[4],
    f32x4 (&acc)[2][4]) {
  bf16x8 af[2][2], bf[2][4];
  wait_vm_chunks(6);                                    // chunk 0 resident (14 issued)
#pragma unroll
  for (int mi = 0; mi < 2; ++mi)
    af[0][mi] = *(const bf16x8*)(ring + aoff[mi]);      // chunk 0, slot 0 (< NCH: breg B)

#pragma unroll
  for (int i = 0; i < LEN; ++i) {
    const int kc  = i;
    const int cur = i & 1, nxt = cur ^ 1;
    if (i + 1 < LEN) {
      wait_vm_chunks(LEN - 2 - i < 5 ? LEN - 2 - i : 5);   // chunk kc+1 resident
      const int kn = kc + 1;
#pragma unroll
      for (int mi = 0; mi < 2; ++mi)
        af[nxt][mi] = *(const bf16x8*)(ring + (kn & 7) * 4096 + aoff[mi]);
      if (kn >= NCH) {
#pragma unroll
        for (int g = 0; g < 4; ++g)
          bf[nxt][g] = *(const bf16x8*)(BsL + (kn - NCH) * 2048 + boff[g]);
        wait_lgkm_n(6);                 // frags of kc done; kc+1's 6 in flight
      } else {
        wait_lgkm_n(2);
      }
      if (i + 7 < LEN) stage_chunk<SPLIT, SA, SB, COHA>(kc + 7, Aa, Ab, m0, w, lane, ring);
    } else {
      wait_lgkm_n(0);
    }
#pragma unroll
    for (int mi = 0; mi < 2; ++mi)
#pragma unroll
      for (int g = 0; g < 4; ++g)
        acc[mi][g] = __builtin_amdgcn_mfma_f32_16x16x32_bf16(
            af[cur][mi], (kc < NCH ? breg[kc][g] : bf[cur][g]), acc[mi][g], 0, 0, 0);
  }
}

template<bool Z2>
__device__ __forceinline__ void role_loop(const Params& p, char* smem, int tid,
                                          int grp, int ntile) {
  constexpr int K   = Z2 ? K2 : K1;
  constexpr int NC  = K / 32;
  const int lane = tid & 63;
  const int w    = tid >> 6;
  const int q    = lane >> 4;
  const int m16  = lane & 15;
  const int m0   = grp * 128;
  const int n0   = ntile * 64;

  __hip_bfloat16* BsL  = (__hip_bfloat16*)smem;
  __hip_bfloat16* ring = (__hip_bfloat16*)(smem + RING_OFF);
  __hip_bfloat16* epi  = (__hip_bfloat16*)(smem + EPI_OFF);

  const __hip_bfloat16* Bg = (Z2 ? p.Wz2t : p.Wz1t) + (size_t)n0 * K;

  // one-time: B chunks 0..NCH-1 into registers (static indexing only)
  bf16x8 breg[NCH][4];
#pragma unroll
  for (int kc = 0; kc < NCH; ++kc)
#pragma unroll
    for (int g = 0; g < 4; ++g)
      breg[kc][g] = *(const bf16x8*)(Bg + (size_t)(g * 16 + m16) * K + kc * 32 + q * 8);

  // one-time: B chunks NCH..NC-1 into LDS, chunk-major granule-swizzled
  for (int it0 = tid; it0 < (NC - NCH) * 256; it0 += 256) {
    int cid = it0 >> 8, gg = it0 & 255;
    int r = gg >> 2, c8 = gg & 3;
    int sw = c8 ^ ((r >> 1) & 3);
    *(bf16x8*)(BsL + cid * 2048 + r * 32 + sw * 8) =
        *(const bf16x8*)(Bg + (size_t)r * K + (NCH + cid) * 32 + c8 * 8);
  }
  const float* bias = Z2 ? p.bz2 : p.bz1;
  float bz[4];
#pragma unroll
  for (int g = 0; g < 4; ++g) bz[g] = bias[n0 + g * 16 + m16];

  const int swz = (q ^ ((m16 >> 1) & 3)) * 8;
  int aoff[2], boff[4];
#pragma unroll
  for (int mi = 0; mi < 2; ++mi) aoff[mi] = (w * 32 + mi * 16 + m16) * 32 + swz;
#pragma unroll
  for (int g = 0; g < 4; ++g)    boff[g]  = (g * 16 + m16) * 32 + swz;

  float cst[2][4] = {{0.f,0.f,0.f,0.f},{0.f,0.f,0.f,0.f}};
  const int fself = (Z2 ? 128 : 0) + grp * 32 + ntile;
  const int jbase = ntile * 16;
  __syncthreads();

  for (int s = 0; s < TSTEPS; ++s) {
    const int sl = s % D_SLOTS, slp = (s + D_SLOTS - 1) % D_SLOTS;
    const __hip_bfloat16* Aa = Z2
        ? (const __hip_bfloat16*)(p.h1base + (size_t)sl * SLOT_BYTES)    // h1[s]
        : p.Xall + (size_t)s * BATCH * EDIM;                             // x[s]
    const __hip_bfloat16* Ab = Z2
        ? (const __hip_bfloat16*)(p.h2base + (size_t)slp * SLOT_BYTES)   // h2[s-1]
        : (const __hip_bfloat16*)(p.h1base + (size_t)slp * SLOT_BYTES);  // h1[s-1]
    __hip_bfloat16* hout = (__hip_bfloat16*)
        ((Z2 ? p.h2base : p.h1base) + (size_t)sl * SLOT_BYTES);

    f32x4 acc[2][4];
#pragma unroll
    for (int mi = 0; mi < 2; ++mi)
#pragma unroll
      for (int g = 0; g < 4; ++g)
        acc[mi][g] = (f32x4){bz[g], bz[g], bz[g], bz[g]};

    // z1: pre-stage immutable X chunks (0..6) BEFORE the gate -- their latency
    // hides under the gate poll. Ring regions are wave-disjoint -> no barrier
    // needed around the pre-fill.
    if (!Z2) {
#pragma unroll
      for (int f = 0; f < 7; ++f)
        stage_chunk<8, EDIM, HDIM, false>(f, Aa, Ab, m0, w, lane, ring);
    }

    // ---- single merged gate (one LLC poll round for both dependencies) ----
    // z2: lanes<32 poll z1 flags >= s+1 (h1[s] fresh), lanes>=32 poll z2 peers
    //     >= s (h2[s-1] fresh; also subsumes the WAR on slot sl).
    // z1: z1 peers >= s (h1[s-1] fresh) + z2 >= s-11 (WAR on slot sl).
    if (w == 0) {
      if (Z2) gate_wave(p.flags, grp * 32, s + 1, 128 + grp * 32, s, lane);
      else    gate_wave(p.flags, grp * 32, s, 128 + grp * 32, s - (D_SLOTS - 1), lane);
      if ((s & 7) == 0) __builtin_amdgcn_fence(__ATOMIC_ACQUIRE, "agent");
    }
    __syncthreads();

    // ---- merged K-stream: part A then part B as one chunk sequence ----
    if (Z2) {
#pragma unroll
      for (int f = 0; f < 7; ++f)
        stage_chunk<16, HDIM, HDIM, true>(f, Aa, Ab, m0, w, lane, ring);
      run_loop<32, 16, HDIM, HDIM, true >(Aa, Ab, m0, w, lane, ring, BsL, breg, aoff, boff, acc);
    } else {
      run_loop<24,  8, EDIM, HDIM, false>(Aa, Ab, m0, w, lane, ring, BsL, breg, aoff, boff, acc);
    }

    // epilogue: gates -> cell state (regs) -> h via LDS transpose.
    // Transpose is WAVE-LOCAL (wave w writes+reads rows 32w..32w+31), so an
    // lgkmcnt(0) replaces the first barrier.
#pragma unroll
    for (int mi = 0; mi < 2; ++mi)
#pragma unroll
      for (int rr = 0; rr < 4; ++rr) {
        const float zi = acc[mi][0][rr], zf = acc[mi][1][rr];
        const float zg = acc[mi][2][rr], zo = acc[mi][3][rr];
        const float cn = sigm(zf) * cst[mi][rr] + sigm(zi) * tanhp(zg);
        cst[mi][rr] = cn;
        epi[(w * 32 + mi * 16 + q * 4 + rr) * EPI_STR + m16] = __float2bfloat16(sigm(zo) * tanhp(cn));
      }
    wait_lgkm_n(0);                                // wave-local transpose ready
    {
      const int r = tid >> 1, hf = tid & 1;
      bf16x8 hv = *(const bf16x8*)(epi + r * EPI_STR + hf * 8);
      coh_store16(hout + (size_t)(m0 + r) * HDIM + jbase + hf * 8, hv);
    }
    WAIT_VM0;                                      // h committed to LLC
    __syncthreads();
    if (tid == 0) flag_store(p.flags + fself * 4, s + 1);
  }
}

__global__ __launch_bounds__(256, 1) void lstm_seq(Params p) {
  extern __shared__ char smem[];
  const int tid = threadIdx.x;
  const bool z2  = ((blockIdx.x & 1) == 0);
  const int grp  = (blockIdx.x >> 1) & 3;
  const int ntile = blockIdx.x >> 3;

  if (z2) role_loop<true>(p, smem, tid, grp, ntile);
  else    role_loop<false>(p, smem, tid, grp, ntile);

  // final FC: block b -> rows {2b, 2b+1}; wait on producing z2 group's flags
  const int lane = tid & 63, w = tid >> 6;
  if (w == 0) {
    const int g2 = blockIdx.x >> 6;
    gate_wave(p.flags, 128 + g2 * 32, TSTEPS, 128 + g2 * 32, TSTEPS, lane);
  }
  __syncthreads();
  if (w < 2) {
    const int row = blockIdx.x * 2 + w;
    const unsigned int* hp = (const unsigned int*)
        (p.h2base + (size_t)((TSTEPS - 1) % D_SLOTS) * SLOT_BYTES) + (size_t)row * (HDIM / 2);
    float sum = 0.f;
#pragma unroll
    for (int cc = 0; cc < 4; ++cc) {
      unsigned int d = coh_load(hp + lane * 4 + cc);
      union { unsigned int ui; float f; } lo, hi;
      lo.ui = d << 16; hi.ui = d & 0xffff0000u;
      sum += lo.f * p.Wfc[(lane * 4 + cc) * 2] + hi.f * p.Wfc[(lane * 4 + cc) * 2 + 1];
    }
#pragma unroll
    for (int o = 32; o > 0; o >>= 1) sum += __shfl_down(sum, o, 64);
    if (lane == 0) p.out[row] = sigm(sum + p.bfc[0]);
  }
}

// ---------------- host launcher ----------------

extern "C" void kernel_launch(void* const* d_in, const int* in_sizes, int n_in,
                              void* d_out, int out_size, void* d_ws, size_t ws_size,
                              hipStream_t stream) {
  const int*   tokens = (const int*)d_in[0];
  const float* emb = (const float*)d_in[1];
  const float* W1  = (const float*)d_in[2];
  const float* U1  = (const float*)d_in[3];
  const float* b1  = (const float*)d_in[4];
  const float* W2  = (const float*)d_in[5];
  const float* U2  = (const float*)d_in[6];
  const float* b2  = (const float*)d_in[7];
  const float* Wfc = (const float*)d_in[8];
  const float* bfc = (const float*)d_in[9];

  char* ws = (char*)d_ws;
  size_t off = 0;
  auto alloc = [&](size_t bytes) {
    char* r = ws + off;
    off += (bytes + 255) & ~(size_t)255;
    return r;
  };
  __hip_bfloat16* Wz1t = (__hip_bfloat16*)alloc(2048UL * K1 * 2);
  __hip_bfloat16* Wz2t = (__hip_bfloat16*)alloc(2048UL * K2 * 2);
  float* bz1 = (float*)alloc(2048 * 4);
  float* bz2 = (float*)alloc(2048 * 4);
  __hip_bfloat16* Xall = (__hip_bfloat16*)alloc((size_t)TSTEPS * BATCH * EDIM * 2);
  // state: 24 h-slots (12 h1 + 12 h2) + flags (4096B), ALL zeroed in prep_gather
  const size_t state_bytes = 24UL * SLOT_BYTES + 4096;   // 12,593,152
  char* state = alloc(state_bytes);

  Params prm;
  prm.h1base = state;
  prm.h2base = state + 12UL * SLOT_BYTES;
  prm.flags  = (int*)(state + 24UL * SLOT_BYTES);

  prep_weights<<<dim3(14352), dim3(256), 0, stream>>>(W1, U1, b1, W2, U2, b2, Wz1t, Wz2t, bz1, bz2);
  prep_gather<<<dim3(10240), dim3(256), 0, stream>>>(tokens, emb, Xall,
                                                     (float4*)state, (int)(state_bytes / 16));

  hipFuncSetAttribute((const void*)lstm_seq,
                      hipFuncAttributeMaxDynamicSharedMemorySize, LDS_BYTES);

  prm.Wz1t = Wz1t; prm.Wz2t = Wz2t; prm.bz1 = bz1; prm.bz2 = bz2;
  prm.Xall = Xall;
  prm.Wfc = Wfc; prm.bfc = bfc;
  prm.out = (float*)d_out;

  lstm_seq<<<dim3(256), dim3(256), LDS_BYTES, stream>>>(prm);
}

// Round 3
// 730.567 us; speedup vs baseline: 1.0813x; 1.0813x over previous
//
#include <hip/hip_runtime.h>
#include <hip/hip_bf16.h>

typedef __bf16  bf16x8 __attribute__((ext_vector_type(8)));
typedef float   f32x4  __attribute__((ext_vector_type(4)));

// global->LDS async, 16B/lane. _C: fully cached (immutable X stream).
// _H: sc0 = bypass L1, allocate L2 (h panels; freshness via 12-deep slot
// rotation + aligned fence every 8 phases -- proven R7).
#define GLOAD16_C(gptr, lptr) \
  __builtin_amdgcn_global_load_lds((const __attribute__((address_space(1))) void*)(gptr), \
                                   (__attribute__((address_space(3))) void*)(lptr), 16, 0, 0)
#define GLOAD16_H(gptr, lptr) \
  __builtin_amdgcn_global_load_lds((const __attribute__((address_space(1))) void*)(gptr), \
                                   (__attribute__((address_space(3))) void*)(lptr), 16, 0, 0x1)

#define WAIT_VM14  asm volatile("s_waitcnt vmcnt(14)" ::: "memory")
#define WAIT_VM12  asm volatile("s_waitcnt vmcnt(12)" ::: "memory")
#define WAIT_VM10  asm volatile("s_waitcnt vmcnt(10)" ::: "memory")
#define WAIT_VM8   asm volatile("s_waitcnt vmcnt(8)"  ::: "memory")
#define WAIT_VM6   asm volatile("s_waitcnt vmcnt(6)"  ::: "memory")
#define WAIT_VM4   asm volatile("s_waitcnt vmcnt(4)"  ::: "memory")
#define WAIT_VM2   asm volatile("s_waitcnt vmcnt(2)"  ::: "memory")
#define WAIT_VM0   asm volatile("s_waitcnt vmcnt(0)"  ::: "memory")

__device__ __forceinline__ void wait_vm_chunks(int n) {   // n chunks (2 vm each) may stay outstanding
  if      (n <= 0) WAIT_VM0;
  else if (n == 1) WAIT_VM2;
  else if (n == 2) WAIT_VM4;
  else if (n == 3) WAIT_VM6;
  else if (n == 4) WAIT_VM8;
  else if (n == 5) WAIT_VM10;
  else             WAIT_VM12;
}
__device__ __forceinline__ void wait_lgkm_n(int n) {
  if      (n <= 0) asm volatile("s_waitcnt lgkmcnt(0)" ::: "memory");
  else if (n <= 2) asm volatile("s_waitcnt lgkmcnt(2)" ::: "memory");
  else             asm volatile("s_waitcnt lgkmcnt(6)" ::: "memory");
}

__device__ __forceinline__ float sigm(float x)  { return 1.0f / (1.0f + __expf(-x)); }
__device__ __forceinline__ float tanhp(float x) { return 2.0f / (1.0f + __expf(-2.0f * x)) - 1.0f; }

// LLC-coherent scalar load / stores (bypass L1/L2)
__device__ __forceinline__ unsigned int coh_load(const unsigned int* p) {
  unsigned int v;
  asm volatile("global_load_dword %0, %1, off sc0 sc1\n\ts_waitcnt vmcnt(0)"
               : "=v"(v) : "v"(p) : "memory");
  return v;
}
__device__ __forceinline__ int coh_load_i(const int* p) {
  int v;
  asm volatile("global_load_dword %0, %1, off sc0 sc1\n\ts_waitcnt vmcnt(0)"
               : "=v"(v) : "v"(p) : "memory");
  return v;
}
__device__ __forceinline__ void coh_store16(void* p, bf16x8 v) {
  f32x4 f = *(f32x4*)&v;
  asm volatile("global_store_dwordx4 %0, %1, off sc0 sc1" :: "v"(p), "v"(f) : "memory");
}
__device__ __forceinline__ void flag_store(int* fp, int v) {
  asm volatile("global_store_dword %0, %1, off sc0 sc1" :: "v"(fp), "v"(v) : "memory");
}

#define TSTEPS 80
#define BATCH  512
#define EDIM   256
#define HDIM   512
#define K2     1024
#define K1     768
#define NCH    16           // B K-chunks in registers/AGPRs
#define D_SLOTS 12
#define SLOT_BYTES 524544   // 512 KB + 256 B guard
// LDS: BsL (<=16 chunks * 4KB = 64KB) | ring (8 * 8KB = 64KB) | epi (128 x 24 bf16)
#define RING_OFF 65536
#define EPI_OFF  131072
#define EPI_STR  24
#define LDS_BYTES 137216

struct Params {
  const __hip_bfloat16* Wz1t;   // [2048][768]  bf16, [N'][K], K-order [W1|U1] (x first)
  const __hip_bfloat16* Wz2t;   // [2048][1024]             K-order [W2|U2] (h1 first)
  const float* bz1;             // [2048] permuted
  const float* bz2;
  const __hip_bfloat16* Xall;   // [80][512][256] bf16
  char* h1base;                 // 12 slots, SLOT_BYTES stride
  char* h2base;                 // 12 slots
  int* flags;                   // 256 entries, 16B stride: z1 at idx, z2 at 128+idx
  const float* Wfc; const float* bfc;
  float* out;
};

// ---------------- prep kernels ----------------
// permuted column: n' = ntile*64 + gate*16 + u  (ntile = j>>4, u = j&15)
// K-order: the TIGHT-gated operand goes LAST:
//   Wz1t: k<256 -> W1[k] (x),  k>=256 -> U1[k-256] (h1[s-1], peer-gated)
//   Wz2t: k<512 -> W2[k] (h1), k>=512 -> U2[k-512] (h2[s-1], peer-gated)

__global__ __launch_bounds__(256) void prep_weights(
    const float* __restrict__ W1, const float* __restrict__ U1, const float* __restrict__ b1,
    const float* __restrict__ W2, const float* __restrict__ U2, const float* __restrict__ b2,
    __hip_bfloat16* __restrict__ Wz1t, __hip_bfloat16* __restrict__ Wz2t,
    float* __restrict__ bz1, float* __restrict__ bz2) {
  long idx = (long)blockIdx.x * 256 + threadIdx.x;
  const long n1 = 2048L * K1, n2 = 2048L * K2;
  if (idx < n1) {
    int n = (int)(idx / K1), k = (int)(idx % K1);
    int col = ((n >> 4) & 3) * 512 + (n >> 6) * 16 + (n & 15);
    float v = (k < 256) ? W1[(size_t)k * 2048 + col] : U1[(size_t)(k - 256) * 2048 + col];
    Wz1t[idx] = __float2bfloat16(v);
  } else if (idx < n1 + n2) {
    long r = idx - n1;
    int n = (int)(r / K2), k = (int)(r % K2);
    int col = ((n >> 4) & 3) * 512 + (n >> 6) * 16 + (n & 15);
    float v = (k < 512) ? W2[(size_t)k * 2048 + col] : U2[(size_t)(k - 512) * 2048 + col];
    Wz2t[r] = __float2bfloat16(v);
  } else if (idx < n1 + n2 + 2048) {
    int n = (int)(idx - (n1 + n2));
    bz1[n] = b1[((n >> 4) & 3) * 512 + (n >> 6) * 16 + (n & 15)];
  } else if (idx < n1 + n2 + 4096) {
    int n = (int)(idx - (n1 + n2 + 2048));
    bz2[n] = b2[((n >> 4) & 3) * 512 + (n >> 6) * 16 + (n & 15)];
  }
}

__global__ __launch_bounds__(256) void prep_gather(
    const int* __restrict__ tokens, const float* __restrict__ emb,
    __hip_bfloat16* __restrict__ Xall, float4* __restrict__ zp, int zn) {
  int idx = blockIdx.x * 256 + threadIdx.x;
  if (idx < zn) zp[idx] = make_float4(0.f, 0.f, 0.f, 0.f);   // zero state+flags
  int e  = (idx & 63) * 4;
  int rb = idx >> 6;            // t*512 + b
  int t  = rb >> 9;
  int b  = rb & 511;
  int tok = tokens[b * TSTEPS + t];
  const float4 v = *(const float4*)&emb[(size_t)tok * EDIM + e];
  __hip_bfloat16* o = Xall + (size_t)rb * EDIM + e;
  o[0] = __float2bfloat16(v.x); o[1] = __float2bfloat16(v.y);
  o[2] = __float2bfloat16(v.z); o[3] = __float2bfloat16(v.w);
}

// ---------------- main kernel ----------------
// R9: R7 gate placement (tight peer gate BETWEEN part A and part B, hidden
// behind part A compute -- R8 proved exposing it at the step top costs
// ~1.2us/step) + step-boundary pipelining: at the tail of step s, the slack
// z1-gate for s+1 runs (instant; z1 ~11 steps ahead), part A chunks 0..6 of
// step s+1 are prefilled, and the h-store drains via vmcnt(14) (store is the
// oldest op) UNDER the prefill -- hiding both the store-drain and the part A
// fill bubble. Lookahead 7; epilogue transpose is wave-local (lgkm, 1 barrier).
// Coherence scheme unchanged from R7 (12-slot rotation, sc0sc1 write-through,
// agent-acquire fence every 8 steps at the tight gate; tail prefill of slot
// (s+1)%12 is fresh since last self-touch was s-11 < last fence >= s-7).

__device__ __forceinline__ void gate_wave(const int* flags, int base1, int t1,
                                          int base2, int t2, int lane) {
  const int idx = lane & 31;
  const int* fp = flags + (((lane < 32) ? base1 : base2) + idx) * 4;   // 16B stride
  const int tgt = (lane < 32) ? t1 : t2;
  for (;;) {
    int v = coh_load_i(fp);
    if (__ballot(v >= tgt) == ~0ull) break;
    __builtin_amdgcn_s_sleep(2);
  }
}

// stage one 8KB K-chunk (per wave: its own 32-row quarter, 2 x 1KB loads).
// kc selects the ring slot (kc&7); kcol the source K-chunk column.
template<int STRIDE, bool COH>
__device__ __forceinline__ void stage_one(const __hip_bfloat16* __restrict__ A,
    int kc, int kcol, int m0, int w, int lane, __hip_bfloat16* __restrict__ ring) {
#pragma unroll
  for (int it = 0; it < 2; ++it) {
    const int gbase = w * 128 + it * 64;
    const int g   = gbase + lane;
    const int row = g >> 2;
    const int gc  = (g & 3) ^ ((row >> 1) & 3);       // XOR swizzle (pre-swizzled source)
    __hip_bfloat16* lp = ring + (kc & 7) * 4096 + gbase * 8;
    const __hip_bfloat16* gp = A + (size_t)(m0 + row) * STRIDE + kcol * 32 + gc * 8;
    if (COH) { GLOAD16_H(gp, lp); } else { GLOAD16_C(gp, lp); }
  }
}

// part loop over chunks K0..K0+LEN-1. If PREFILLED, chunks K0..K0+6 were
// already issued by the caller (slots (K0..K0+6)&7, matching addressing).
// Steady state: stage(kc+7), wait allows 5 chunks outstanding (kc+1 resident).
// Slot (kc+7)&7 == (kc-1)&7: chunk kc-1's ds_reads retired at the previous
// iteration's lgkm wait -> overwrite safe. Ends fully drained (vm0, lgkm0).
template<int K0, int LEN, int STRIDE, bool COH, bool PREFILLED>
__device__ __forceinline__ void run_part(
    const __hip_bfloat16* __restrict__ A, int m0, int w, int lane,
    __hip_bfloat16* __restrict__ ring, const __hip_bfloat16* __restrict__ BsL,
    const bf16x8 (&breg)[NCH][4], const int (&aoff)[2], const int (&boff)[4],
    f32x4 (&acc)[2][4]) {
  if (!PREFILLED) {
#pragma unroll
    for (int f = 0; f < 7; ++f)
      stage_one<STRIDE, COH>(A, K0 + f, f, m0, w, lane, ring);
  }
  bf16x8 af[2][2], bf[2][4];
  wait_vm_chunks(6);                                    // chunk K0 resident (14 issued)
#pragma unroll
  for (int mi = 0; mi < 2; ++mi)
    af[0][mi] = *(const bf16x8*)(ring + (K0 & 7) * 4096 + aoff[mi]);
  if (K0 >= NCH)
#pragma unroll
    for (int g = 0; g < 4; ++g)
      bf[0][g] = *(const bf16x8*)(BsL + (K0 - NCH) * 2048 + boff[g]);

#pragma unroll
  for (int i = 0; i < LEN; ++i) {
    const int kc  = K0 + i;
    const int cur = i & 1, nxt = cur ^ 1;
    if (i + 1 < LEN) {
      wait_vm_chunks(LEN - 2 - i < 5 ? LEN - 2 - i : 5);   // chunk kc+1 resident
      const int kn = kc + 1;
#pragma unroll
      for (int mi = 0; mi < 2; ++mi)
        af[nxt][mi] = *(const bf16x8*)(ring + (kn & 7) * 4096 + aoff[mi]);
      if (kn >= NCH) {
#pragma unroll
        for (int g = 0; g < 4; ++g)
          bf[nxt][g] = *(const bf16x8*)(BsL + (kn - NCH) * 2048 + boff[g]);
        wait_lgkm_n(6);                 // frags of kc done; kc+1's 6 in flight
      } else {
        wait_lgkm_n(2);
      }
      if (i + 7 < LEN) stage_one<STRIDE, COH>(A, kc + 7, i + 7, m0, w, lane, ring);
    } else {
      wait_lgkm_n(0);
    }
#pragma unroll
    for (int mi = 0; mi < 2; ++mi)
#pragma unroll
      for (int g = 0; g < 4; ++g)
        acc[mi][g] = __builtin_amdgcn_mfma_f32_16x16x32_bf16(
            af[cur][mi], (kc < NCH ? breg[kc][g] : bf[cur][g]), acc[mi][g], 0, 0, 0);
  }
}

template<bool Z2>
__device__ __forceinline__ void role_loop(const Params& p, char* smem, int tid,
                                          int grp, int ntile) {
  constexpr int K   = Z2 ? K2 : K1;
  constexpr int NC  = K / 32;
  constexpr int LENA = Z2 ? 16 : 8;      // part-A chunks (h1 / x)
  const int lane = tid & 63;
  const int w    = tid >> 6;
  const int q    = lane >> 4;
  const int m16  = lane & 15;
  const int m0   = grp * 128;
  const int n0   = ntile * 64;

  __hip_bfloat16* BsL  = (__hip_bfloat16*)smem;
  __hip_bfloat16* ring = (__hip_bfloat16*)(smem + RING_OFF);
  __hip_bfloat16* epi  = (__hip_bfloat16*)(smem + EPI_OFF);

  const __hip_bfloat16* Bg = (Z2 ? p.Wz2t : p.Wz1t) + (size_t)n0 * K;

  // one-time: B chunks 0..NCH-1 into registers (static indexing only)
  bf16x8 breg[NCH][4];
#pragma unroll
  for (int kc = 0; kc < NCH; ++kc)
#pragma unroll
    for (int g = 0; g < 4; ++g)
      breg[kc][g] = *(const bf16x8*)(Bg + (size_t)(g * 16 + m16) * K + kc * 32 + q * 8);

  // one-time: B chunks NCH..NC-1 into LDS, chunk-major granule-swizzled
  for (int it0 = tid; it0 < (NC - NCH) * 256; it0 += 256) {
    int cid = it0 >> 8, gg = it0 & 255;
    int r = gg >> 2, c8 = gg & 3;
    int sw = c8 ^ ((r >> 1) & 3);
    *(bf16x8*)(BsL + cid * 2048 + r * 32 + sw * 8) =
        *(const bf16x8*)(Bg + (size_t)r * K + (NCH + cid) * 32 + c8 * 8);
  }
  const float* bias = Z2 ? p.bz2 : p.bz1;
  float bz[4];
#pragma unroll
  for (int g = 0; g < 4; ++g) bz[g] = bias[n0 + g * 16 + m16];

  const int swz = (q ^ ((m16 >> 1) & 3)) * 8;
  int aoff[2], boff[4];
#pragma unroll
  for (int mi = 0; mi < 2; ++mi) aoff[mi] = (w * 32 + mi * 16 + m16) * 32 + swz;
#pragma unroll
  for (int g = 0; g < 4; ++g)    boff[g]  = (g * 16 + m16) * 32 + swz;

  float cst[2][4] = {{0.f,0.f,0.f,0.f},{0.f,0.f,0.f,0.f}};
  const int fself = (Z2 ? 128 : 0) + grp * 32 + ntile;
  const int jbase = ntile * 16;
  __syncthreads();

  // pre-loop: prefill part A of step 0 (z2: slack gate on z1 first)
  if (Z2) {
    if (w == 0) gate_wave(p.flags, grp * 32, 1, grp * 32, 1, lane);
    __syncthreads();
  }
  {
    const __hip_bfloat16* A0 = Z2
        ? (const __hip_bfloat16*)p.h1base            // h1 slot 0
        : p.Xall;                                    // x[0]
#pragma unroll
    for (int f = 0; f < 7; ++f)
      stage_one<(Z2 ? HDIM : EDIM), Z2>(A0, f, f, m0, w, lane, ring);
  }

  for (int s = 0; s < TSTEPS; ++s) {
    const int sl = s % D_SLOTS, slp = (s + D_SLOTS - 1) % D_SLOTS;
    const __hip_bfloat16* Aa = Z2
        ? (const __hip_bfloat16*)(p.h1base + (size_t)sl * SLOT_BYTES)    // h1[s]
        : p.Xall + (size_t)s * BATCH * EDIM;                             // x[s]
    const __hip_bfloat16* Ab = Z2
        ? (const __hip_bfloat16*)(p.h2base + (size_t)slp * SLOT_BYTES)   // h2[s-1]
        : (const __hip_bfloat16*)(p.h1base + (size_t)slp * SLOT_BYTES);  // h1[s-1]
    __hip_bfloat16* hout = (__hip_bfloat16*)
        ((Z2 ? p.h2base : p.h1base) + (size_t)sl * SLOT_BYTES);

    f32x4 acc[2][4];
#pragma unroll
    for (int mi = 0; mi < 2; ++mi)
#pragma unroll
      for (int g = 0; g < 4; ++g)
        acc[mi][g] = (f32x4){bz[g], bz[g], bz[g], bz[g]};

    // ---- part A (prefilled at the tail of the previous step) ----
    if (Z2) run_part<0, 16, HDIM, true,  true>(Aa, m0, w, lane, ring, BsL, breg, aoff, boff, acc);
    else    run_part<0,  8, EDIM, false, true>(Aa, m0, w, lane, ring, BsL, breg, aoff, boff, acc);

    // ---- tight peer gate (hidden behind part A compute) + fence cadence ----
    if (w == 0) {
      if (Z2) gate_wave(p.flags, 128 + grp * 32, s, 128 + grp * 32, s, lane);
      else    gate_wave(p.flags, grp * 32, s, 128 + grp * 32, s - (D_SLOTS - 1), lane);
      if ((s & 7) == 0) __builtin_amdgcn_fence(__ATOMIC_ACQUIRE, "agent");
    }
    __syncthreads();

    // ---- part B (tight-gated operand) ----
    if (Z2) run_part<16, 16, HDIM, true, false>(Ab, m0, w, lane, ring, BsL, breg, aoff, boff, acc);
    else    run_part< 8, 16, HDIM, true, false>(Ab, m0, w, lane, ring, BsL, breg, aoff, boff, acc);

    // epilogue: gates -> cell state (regs) -> h via LDS transpose.
    // Transpose is WAVE-LOCAL (wave w writes+reads rows 32w..32w+31).
#pragma unroll
    for (int mi = 0; mi < 2; ++mi)
#pragma unroll
      for (int rr = 0; rr < 4; ++rr) {
        const float zi = acc[mi][0][rr], zf = acc[mi][1][rr];
        const float zg = acc[mi][2][rr], zo = acc[mi][3][rr];
        const float cn = sigm(zf) * cst[mi][rr] + sigm(zi) * tanhp(zg);
        cst[mi][rr] = cn;
        epi[(w * 32 + mi * 16 + q * 4 + rr) * EPI_STR + m16] = __float2bfloat16(sigm(zo) * tanhp(cn));
      }
    wait_lgkm_n(0);                                // wave-local transpose ready
    {
      const int r = tid >> 1, hf = tid & 1;
      bf16x8 hv = *(const bf16x8*)(epi + r * EPI_STR + hf * 8);
      coh_store16(hout + (size_t)(m0 + r) * HDIM + jbase + hf * 8, hv);
    }

    // ---- tail: hide store-drain + next step's part A fill ----
    if (s + 1 < TSTEPS) {
      if (Z2) {
        if (w == 0) gate_wave(p.flags, grp * 32, s + 2, grp * 32, s + 2, lane);  // slack gate
        __syncthreads();                            // orders prefill after gate
        const __hip_bfloat16* An =
            (const __hip_bfloat16*)(p.h1base + (size_t)((s + 1) % D_SLOTS) * SLOT_BYTES);
#pragma unroll
        for (int f = 0; f < 7; ++f)
          stage_one<HDIM, true>(An, f, f, m0, w, lane, ring);
      } else {
        const __hip_bfloat16* An = p.Xall + (size_t)(s + 1) * BATCH * EDIM;
#pragma unroll
        for (int f = 0; f < 7; ++f)
          stage_one<EDIM, false>(An, f, f, m0, w, lane, ring);
      }
      WAIT_VM14;                                    // store (oldest) retired; prefill in flight
      __syncthreads();
      if (tid == 0) flag_store(p.flags + fself * 4, s + 1);
    } else {
      WAIT_VM0;                                     // final step: plain drain
      __syncthreads();
      if (tid == 0) flag_store(p.flags + fself * 4, s + 1);
    }
  }
}

__global__ __launch_bounds__(256, 1) void lstm_seq(Params p) {
  extern __shared__ char smem[];
  const int tid = threadIdx.x;
  const bool z2  = ((blockIdx.x & 1) == 0);
  const int grp  = (blockIdx.x >> 1) & 3;
  const int ntile = blockIdx.x >> 3;

  if (z2) role_loop<true>(p, smem, tid, grp, ntile);
  else    role_loop<false>(p, smem, tid, grp, ntile);

  // final FC: block b -> rows {2b, 2b+1}; wait on producing z2 group's flags
  const int lane = tid & 63, w = tid >> 6;
  if (w == 0) {
    const int g2 = blockIdx.x >> 6;
    gate_wave(p.flags, 128 + g2 * 32, TSTEPS, 128 + g2 * 32, TSTEPS, lane);
  }
  __syncthreads();
  if (w < 2) {
    const int row = blockIdx.x * 2 + w;
    const unsigned int* hp = (const unsigned int*)
        (p.h2base + (size_t)((TSTEPS - 1) % D_SLOTS) * SLOT_BYTES) + (size_t)row * (HDIM / 2);
    float sum = 0.f;
#pragma unroll
    for (int cc = 0; cc < 4; ++cc) {
      unsigned int d = coh_load(hp + lane * 4 + cc);
      union { unsigned int ui; float f; } lo, hi;
      lo.ui = d << 16; hi.ui = d & 0xffff0000u;
      sum += lo.f * p.Wfc[(lane * 4 + cc) * 2] + hi.f * p.Wfc[(lane * 4 + cc) * 2 + 1];
    }
#pragma unroll
    for (int o = 32; o > 0; o >>= 1) sum += __shfl_down(sum, o, 64);
    if (lane == 0) p.out[row] = sigm(sum + p.bfc[0]);
  }
}

// ---------------- host launcher ----------------

extern "C" void kernel_launch(void* const* d_in, const int* in_sizes, int n_in,
                              void* d_out, int out_size, void* d_ws, size_t ws_size,
                              hipStream_t stream) {
  const int*   tokens = (const int*)d_in[0];
  const float* emb = (const float*)d_in[1];
  const float* W1  = (const float*)d_in[2];
  const float* U1  = (const float*)d_in[3];
  const float* b1  = (const float*)d_in[4];
  const float* W2  = (const float*)d_in[5];
  const float* U2  = (const float*)d_in[6];
  const float* b2  = (const float*)d_in[7];
  const float* Wfc = (const float*)d_in[8];
  const float* bfc = (const float*)d_in[9];

  char* ws = (char*)d_ws;
  size_t off = 0;
  auto alloc = [&](size_t bytes) {
    char* r = ws + off;
    off += (bytes + 255) & ~(size_t)255;
    return r;
  };
  __hip_bfloat16* Wz1t = (__hip_bfloat16*)alloc(2048UL * K1 * 2);
  __hip_bfloat16* Wz2t = (__hip_bfloat16*)alloc(2048UL * K2 * 2);
  float* bz1 = (float*)alloc(2048 * 4);
  float* bz2 = (float*)alloc(2048 * 4);
  __hip_bfloat16* Xall = (__hip_bfloat16*)alloc((size_t)TSTEPS * BATCH * EDIM * 2);
  // state: 24 h-slots (12 h1 + 12 h2) + flags (4096B), ALL zeroed in prep_gather
  const size_t state_bytes = 24UL * SLOT_BYTES + 4096;   // 12,593,152
  char* state = alloc(state_bytes);

  Params prm;
  prm.h1base = state;
  prm.h2base = state + 12UL * SLOT_BYTES;
  prm.flags  = (int*)(state + 24UL * SLOT_BYTES);

  prep_weights<<<dim3(14352), dim3(256), 0, stream>>>(W1, U1, b1, W2, U2, b2, Wz1t, Wz2t, bz1, bz2);
  prep_gather<<<dim3(10240), dim3(256), 0, stream>>>(tokens, emb, Xall,
                                                     (float4*)state, (int)(state_bytes / 16));

  hipFuncSetAttribute((const void*)lstm_seq,
                      hipFuncAttributeMaxDynamicSharedMemorySize, LDS_BYTES);

  prm.Wz1t = Wz1t; prm.Wz2t = Wz2t; prm.bz1 = bz1; prm.bz2 = bz2;
  prm.Xall = Xall;
  prm.Wfc = Wfc; prm.bfc = bfc;
  prm.out = (float*)d_out;

  lstm_seq<<<dim3(256), dim3(256), LDS_BYTES, stream>>>(prm);
}

// Round 4
// 696.034 us; speedup vs baseline: 1.1349x; 1.0496x over previous
//
#include <hip/hip_runtime.h>
#include <hip/hip_bf16.h>

typedef __bf16  bf16x8 __attribute__((ext_vector_type(8)));
typedef float   f32x4  __attribute__((ext_vector_type(4)));

// global->LDS async, 16B/lane. _C: fully cached (immutable X stream).
// _H: sc0 = bypass L1, allocate L2 (h panels; freshness via 12-deep slot
// rotation + aligned fence every 8 phases -- proven R7).
#define GLOAD16_C(gptr, lptr) \
  __builtin_amdgcn_global_load_lds((const __attribute__((address_space(1))) void*)(gptr), \
                                   (__attribute__((address_space(3))) void*)(lptr), 16, 0, 0)
#define GLOAD16_H(gptr, lptr) \
  __builtin_amdgcn_global_load_lds((const __attribute__((address_space(1))) void*)(gptr), \
                                   (__attribute__((address_space(3))) void*)(lptr), 16, 0, 0x1)

#define WAIT_VM10  asm volatile("s_waitcnt vmcnt(10)" ::: "memory")
#define WAIT_VM8   asm volatile("s_waitcnt vmcnt(8)"  ::: "memory")
#define WAIT_VM6   asm volatile("s_waitcnt vmcnt(6)"  ::: "memory")
#define WAIT_VM4   asm volatile("s_waitcnt vmcnt(4)"  ::: "memory")
#define WAIT_VM2   asm volatile("s_waitcnt vmcnt(2)"  ::: "memory")
#define WAIT_VM0   asm volatile("s_waitcnt vmcnt(0)"  ::: "memory")

__device__ __forceinline__ void wait_vm_chunks(int n) {   // n chunks (2 vm each) may stay outstanding
  if      (n <= 0) WAIT_VM0;
  else if (n == 1) WAIT_VM2;
  else if (n == 2) WAIT_VM4;
  else if (n == 3) WAIT_VM6;
  else if (n == 4) WAIT_VM8;
  else             WAIT_VM10;
}
__device__ __forceinline__ void wait_lgkm_n(int n) {
  if      (n <= 0) asm volatile("s_waitcnt lgkmcnt(0)" ::: "memory");
  else if (n <= 2) asm volatile("s_waitcnt lgkmcnt(2)" ::: "memory");
  else             asm volatile("s_waitcnt lgkmcnt(6)" ::: "memory");
}

__device__ __forceinline__ float sigm(float x)  { return 1.0f / (1.0f + __expf(-x)); }
__device__ __forceinline__ float tanhp(float x) { return 2.0f / (1.0f + __expf(-2.0f * x)) - 1.0f; }

// LLC-coherent scalar load / stores (bypass L1/L2)
__device__ __forceinline__ unsigned int coh_load(const unsigned int* p) {
  unsigned int v;
  asm volatile("global_load_dword %0, %1, off sc0 sc1\n\ts_waitcnt vmcnt(0)"
               : "=v"(v) : "v"(p) : "memory");
  return v;
}
__device__ __forceinline__ int coh_load_i(const int* p) {
  int v;
  asm volatile("global_load_dword %0, %1, off sc0 sc1\n\ts_waitcnt vmcnt(0)"
               : "=v"(v) : "v"(p) : "memory");
  return v;
}
__device__ __forceinline__ void coh_store16(void* p, bf16x8 v) {
  f32x4 f = *(f32x4*)&v;
  asm volatile("global_store_dwordx4 %0, %1, off sc0 sc1" :: "v"(p), "v"(f) : "memory");
}
__device__ __forceinline__ void flag_store(int* fp, int v) {
  asm volatile("global_store_dword %0, %1, off sc0 sc1" :: "v"(fp), "v"(v) : "memory");
}

#define TSTEPS 80
#define BATCH  512
#define EDIM   256
#define HDIM   512
#define K2     1024
#define K1     768
#define NCH    16           // B K-chunks in registers (256 VGPR; 1 wave/SIMD -> budget 512)
#define D_SLOTS 12
#define SLOT_BYTES 524544   // 512 KB + 256 B guard
// LDS: BsL (<=16 chunks * 4KB = 64KB) | ring (8 * 8KB = 64KB) | epi (128 x 24 bf16)
#define RING_OFF 65536
#define EPI_OFF  131072
#define EPI_STR  24
#define LDS_BYTES 137216

struct Params {
  const __hip_bfloat16* Wz1t;   // [2048][768]  bf16, [N'][K], K-order [W1|U1] (x first)
  const __hip_bfloat16* Wz2t;   // [2048][1024]             K-order [W2|U2] (h1 first)
  const float* bz1;             // [2048] permuted
  const float* bz2;
  const __hip_bfloat16* Xall;   // [80][512][256] bf16
  char* h1base;                 // 12 slots, SLOT_BYTES stride
  char* h2base;                 // 12 slots
  int* flags;                   // 256 entries, 16B stride: z1 at idx, z2 at 128+idx
  const float* Wfc; const float* bfc;
  float* out;
};

// ---------------- prep kernels ----------------
// permuted column: n' = ntile*64 + gate*16 + u  (ntile = j>>4, u = j&15)
// K-order: the TIGHT-gated operand goes LAST:
//   Wz1t: k<256 -> W1[k] (x),  k>=256 -> U1[k-256] (h1[s-1], peer-gated)
//   Wz2t: k<512 -> W2[k] (h1), k>=512 -> U2[k-512] (h2[s-1], peer-gated)

__global__ __launch_bounds__(256) void prep_weights(
    const float* __restrict__ W1, const float* __restrict__ U1, const float* __restrict__ b1,
    const float* __restrict__ W2, const float* __restrict__ U2, const float* __restrict__ b2,
    __hip_bfloat16* __restrict__ Wz1t, __hip_bfloat16* __restrict__ Wz2t,
    float* __restrict__ bz1, float* __restrict__ bz2) {
  long idx = (long)blockIdx.x * 256 + threadIdx.x;
  const long n1 = 2048L * K1, n2 = 2048L * K2;
  if (idx < n1) {
    int n = (int)(idx / K1), k = (int)(idx % K1);
    int col = ((n >> 4) & 3) * 512 + (n >> 6) * 16 + (n & 15);
    float v = (k < 256) ? W1[(size_t)k * 2048 + col] : U1[(size_t)(k - 256) * 2048 + col];
    Wz1t[idx] = __float2bfloat16(v);
  } else if (idx < n1 + n2) {
    long r = idx - n1;
    int n = (int)(r / K2), k = (int)(r % K2);
    int col = ((n >> 4) & 3) * 512 + (n >> 6) * 16 + (n & 15);
    float v = (k < 512) ? W2[(size_t)k * 2048 + col] : U2[(size_t)(k - 512) * 2048 + col];
    Wz2t[r] = __float2bfloat16(v);
  } else if (idx < n1 + n2 + 2048) {
    int n = (int)(idx - (n1 + n2));
    bz1[n] = b1[((n >> 4) & 3) * 512 + (n >> 6) * 16 + (n & 15)];
  } else if (idx < n1 + n2 + 4096) {
    int n = (int)(idx - (n1 + n2 + 2048));
    bz2[n] = b2[((n >> 4) & 3) * 512 + (n >> 6) * 16 + (n & 15)];
  }
}

__global__ __launch_bounds__(256) void prep_gather(
    const int* __restrict__ tokens, const float* __restrict__ emb,
    __hip_bfloat16* __restrict__ Xall, float4* __restrict__ zp, int zn) {
  int idx = blockIdx.x * 256 + threadIdx.x;
  if (idx < zn) zp[idx] = make_float4(0.f, 0.f, 0.f, 0.f);   // zero state+flags
  int e  = (idx & 63) * 4;
  int rb = idx >> 6;            // t*512 + b
  int t  = rb >> 9;
  int b  = rb & 511;
  int tok = tokens[b * TSTEPS + t];
  const float4 v = *(const float4*)&emb[(size_t)tok * EDIM + e];
  __hip_bfloat16* o = Xall + (size_t)rb * EDIM + e;
  o[0] = __float2bfloat16(v.x); o[1] = __float2bfloat16(v.y);
  o[2] = __float2bfloat16(v.z); o[3] = __float2bfloat16(v.w);
}

// ---------------- main kernel ----------------
// R10 = R0 (proven 630us) + ONE delta: the z2 slack gate (z1 >= s+1, always
// satisfied since z1 runs ~11 steps ahead) moves from the step TOP (where its
// ~0.5-0.7us LLC poll round was serial every step) into the PREVIOUS step's
// tail, between the h-store and WAIT_VM0 -- the poll's internal vmcnt(0)
// subsumes the store drain, so the flag_store is not delayed. Step 0 gets a
// pre-loop gate. R8 proved the TIGHT peer gate must stay hidden behind part-A
// compute (moving it to the top cost 1.2us/step); R9's tail-prefill variant
// cost 0.2us/step net -- both reverted. Everything else byte-identical to R0.

__device__ __forceinline__ void gate_wave(const int* flags, int base1, int t1,
                                          int base2, int t2, int lane) {
  const int idx = lane & 31;
  const int* fp = flags + (((lane < 32) ? base1 : base2) + idx) * 4;   // 16B stride
  const int tgt = (lane < 32) ? t1 : t2;
  for (;;) {
    int v = coh_load_i(fp);
    if (__ballot(v >= tgt) == ~0ull) break;
    __builtin_amdgcn_s_sleep(2);
  }
}

template<int K0, int LEN, int STRIDE, bool COH>
__device__ __forceinline__ void run_part(
    const __hip_bfloat16* __restrict__ Asrc, int m0, int w, int lane,
    __hip_bfloat16* __restrict__ ring, const __hip_bfloat16* __restrict__ BsL,
    const bf16x8 (&breg)[NCH][4], const int (&aoff)[2], const int (&boff)[4],
    f32x4 (&acc)[2][4]) {
  auto stage = [&](int kc) {
#pragma unroll
    for (int it = 0; it < 2; ++it) {
      const int gbase = w * 128 + it * 64;
      const int g   = gbase + lane;
      const int row = g >> 2;
      const int gc  = (g & 3) ^ ((row >> 1) & 3);       // XOR swizzle
      __hip_bfloat16* lp = ring + (kc & 7) * 4096 + gbase * 8;
      const __hip_bfloat16* gp = Asrc + (size_t)(m0 + row) * STRIDE + (kc - K0) * 32 + gc * 8;
      if (COH) GLOAD16_H(gp, lp); else GLOAD16_C(gp, lp);
    }
  };
#pragma unroll
  for (int f = 0; f < 6; ++f) stage(K0 + f);            // fill (LEN >= 8 always)

  bf16x8 af[2][2], bf[2][4];
  wait_vm_chunks(5);                                    // chunk K0 resident
#pragma unroll
  for (int mi = 0; mi < 2; ++mi)
    af[0][mi] = *(const bf16x8*)(ring + (K0 & 7) * 4096 + aoff[mi]);
  if (K0 >= NCH)
#pragma unroll
    for (int g = 0; g < 4; ++g)
      bf[0][g] = *(const bf16x8*)(BsL + (K0 - NCH) * 2048 + boff[g]);

#pragma unroll
  for (int i = 0; i < LEN; ++i) {
    const int kc  = K0 + i;
    const int cur = i & 1, nxt = cur ^ 1;
    if (i + 1 < LEN) {
      wait_vm_chunks(LEN - 2 - i < 4 ? LEN - 2 - i : 4);   // chunk kc+1 resident
      const int kn = kc + 1;
#pragma unroll
      for (int mi = 0; mi < 2; ++mi)
        af[nxt][mi] = *(const bf16x8*)(ring + (kn & 7) * 4096 + aoff[mi]);
      if (kn >= NCH) {
#pragma unroll
        for (int g = 0; g < 4; ++g)
          bf[nxt][g] = *(const bf16x8*)(BsL + (kn - NCH) * 2048 + boff[g]);
        wait_lgkm_n(6);                 // frags of kc done; kc+1's 6 in flight
      } else {
        wait_lgkm_n(2);
      }
      if (i + 6 < LEN) stage(kc + 6);   // slot (kc+6)&7: read 2 iters ago -> free
    } else {
      wait_lgkm_n(0);
    }
#pragma unroll
    for (int mi = 0; mi < 2; ++mi)
#pragma unroll
      for (int g = 0; g < 4; ++g)
        acc[mi][g] = __builtin_amdgcn_mfma_f32_16x16x32_bf16(
            af[cur][mi], (kc < NCH ? breg[kc][g] : bf[cur][g]), acc[mi][g], 0, 0, 0);
  }
}

template<bool Z2>
__device__ __forceinline__ void role_loop(const Params& p, char* smem, int tid,
                                          int grp, int ntile) {
  constexpr int K   = Z2 ? K2 : K1;
  constexpr int NC  = K / 32;
  const int lane = tid & 63;
  const int w    = tid >> 6;
  const int q    = lane >> 4;
  const int m16  = lane & 15;
  const int m0   = grp * 128;
  const int n0   = ntile * 64;

  __hip_bfloat16* BsL  = (__hip_bfloat16*)smem;
  __hip_bfloat16* ring = (__hip_bfloat16*)(smem + RING_OFF);
  __hip_bfloat16* epi  = (__hip_bfloat16*)(smem + EPI_OFF);

  const __hip_bfloat16* Bg = (Z2 ? p.Wz2t : p.Wz1t) + (size_t)n0 * K;

  // one-time: B chunks 0..NCH-1 into registers (static indexing only)
  bf16x8 breg[NCH][4];
#pragma unroll
  for (int kc = 0; kc < NCH; ++kc)
#pragma unroll
    for (int g = 0; g < 4; ++g)
      breg[kc][g] = *(const bf16x8*)(Bg + (size_t)(g * 16 + m16) * K + kc * 32 + q * 8);

  // one-time: B chunks NCH..NC-1 into LDS, chunk-major granule-swizzled
  for (int it0 = tid; it0 < (NC - NCH) * 256; it0 += 256) {
    int cid = it0 >> 8, gg = it0 & 255;
    int r = gg >> 2, c8 = gg & 3;
    int sw = c8 ^ ((r >> 1) & 3);
    *(bf16x8*)(BsL + cid * 2048 + r * 32 + sw * 8) =
        *(const bf16x8*)(Bg + (size_t)r * K + (NCH + cid) * 32 + c8 * 8);
  }
  const float* bias = Z2 ? p.bz2 : p.bz1;
  float bz[4];
#pragma unroll
  for (int g = 0; g < 4; ++g) bz[g] = bias[n0 + g * 16 + m16];

  const int swz = (q ^ ((m16 >> 1) & 3)) * 8;
  int aoff[2], boff[4];
#pragma unroll
  for (int mi = 0; mi < 2; ++mi) aoff[mi] = (w * 32 + mi * 16 + m16) * 32 + swz;
#pragma unroll
  for (int g = 0; g < 4; ++g)    boff[g]  = (g * 16 + m16) * 32 + swz;

  float cst[2][4] = {{0.f,0.f,0.f,0.f},{0.f,0.f,0.f,0.f}};
  const int fself = (Z2 ? 128 : 0) + grp * 32 + ntile;
  const int jbase = ntile * 16;
  __syncthreads();

  // pre-loop: z2's slack gate for step 0 (z1 >= 1 -> h1[0] committed)
  if (Z2) {
    if (w == 0) gate_wave(p.flags, grp * 32, 1, grp * 32, 1, lane);
    __syncthreads();
  }

  for (int s = 0; s < TSTEPS; ++s) {
    const int sl = s % D_SLOTS, slp = (s + D_SLOTS - 1) % D_SLOTS;
    const __hip_bfloat16* Aa = Z2
        ? (const __hip_bfloat16*)(p.h1base + (size_t)sl * SLOT_BYTES)    // h1[s]
        : p.Xall + (size_t)s * BATCH * EDIM;                             // x[s]
    const __hip_bfloat16* Ab = Z2
        ? (const __hip_bfloat16*)(p.h2base + (size_t)slp * SLOT_BYTES)   // h2[s-1]
        : (const __hip_bfloat16*)(p.h1base + (size_t)slp * SLOT_BYTES);  // h1[s-1]
    __hip_bfloat16* hout = (__hip_bfloat16*)
        ((Z2 ? p.h2base : p.h1base) + (size_t)sl * SLOT_BYTES);

    f32x4 acc[2][4];
#pragma unroll
    for (int mi = 0; mi < 2; ++mi)
#pragma unroll
      for (int g = 0; g < 4; ++g)
        acc[mi][g] = (f32x4){bz[g], bz[g], bz[g], bz[g]};

    // ---- part A (z2 slack gate already satisfied in previous tail) ----
    if (Z2) run_part<0, 16, 512, true >(Aa, m0, w, lane, ring, BsL, breg, aoff, boff, acc);
    else    run_part<0,  8, 256, false>(Aa, m0, w, lane, ring, BsL, breg, aoff, boff, acc);

    // ---- part B gate (tight peer RAW, hidden behind part A) + fence ----
    if (w == 0) {
      if (Z2) gate_wave(p.flags, 128 + grp * 32, s, 128 + grp * 32, s, lane);
      else    gate_wave(p.flags, grp * 32, s, 128 + grp * 32, s - (D_SLOTS - 1), lane);
      if ((s & 7) == 0) __builtin_amdgcn_fence(__ATOMIC_ACQUIRE, "agent");
    }
    __syncthreads();
    if (Z2) run_part<16, 16, 512, true>(Ab, m0, w, lane, ring, BsL, breg, aoff, boff, acc);
    else    run_part< 8, 16, 512, true>(Ab, m0, w, lane, ring, BsL, breg, aoff, boff, acc);

    // epilogue: gates -> cell state (regs) -> h via LDS transpose
#pragma unroll
    for (int mi = 0; mi < 2; ++mi)
#pragma unroll
      for (int rr = 0; rr < 4; ++rr) {
        const float zi = acc[mi][0][rr], zf = acc[mi][1][rr];
        const float zg = acc[mi][2][rr], zo = acc[mi][3][rr];
        const float cn = sigm(zf) * cst[mi][rr] + sigm(zi) * tanhp(zg);
        cst[mi][rr] = cn;
        epi[(w * 32 + mi * 16 + q * 4 + rr) * EPI_STR + m16] = __float2bfloat16(sigm(zo) * tanhp(cn));
      }
    __syncthreads();
    {
      const int r = tid >> 1, hf = tid & 1;
      bf16x8 hv = *(const bf16x8*)(epi + r * EPI_STR + hf * 8);
      coh_store16(hout + (size_t)(m0 + r) * HDIM + jbase + hf * 8, hv);
    }
    // z2: next step's slack gate polls here -- its vmcnt(0) subsumes the
    // store drain, so flag_store is not delayed. (z1 lead >= 2 in steady
    // state; startup transient only at s=0.)
    if (Z2 && w == 0 && s + 1 < TSTEPS)
      gate_wave(p.flags, grp * 32, s + 2, grp * 32, s + 2, lane);
    WAIT_VM0;                                      // h committed to LLC
    __syncthreads();
    if (tid == 0) flag_store(p.flags + fself * 4, s + 1);
  }
}

__global__ __launch_bounds__(256, 1) void lstm_seq(Params p) {
  extern __shared__ char smem[];
  const int tid = threadIdx.x;
  const bool z2  = ((blockIdx.x & 1) == 0);
  const int grp  = (blockIdx.x >> 1) & 3;
  const int ntile = blockIdx.x >> 3;

  if (z2) role_loop<true>(p, smem, tid, grp, ntile);
  else    role_loop<false>(p, smem, tid, grp, ntile);

  // final FC: block b -> rows {2b, 2b+1}; wait on producing z2 group's flags
  const int lane = tid & 63, w = tid >> 6;
  if (w == 0) {
    const int g2 = blockIdx.x >> 6;
    gate_wave(p.flags, 128 + g2 * 32, TSTEPS, 128 + g2 * 32, TSTEPS, lane);
  }
  __syncthreads();
  if (w < 2) {
    const int row = blockIdx.x * 2 + w;
    const unsigned int* hp = (const unsigned int*)
        (p.h2base + (size_t)((TSTEPS - 1) % D_SLOTS) * SLOT_BYTES) + (size_t)row * (HDIM / 2);
    float sum = 0.f;
#pragma unroll
    for (int cc = 0; cc < 4; ++cc) {
      unsigned int d = coh_load(hp + lane * 4 + cc);
      union { unsigned int ui; float f; } lo, hi;
      lo.ui = d << 16; hi.ui = d & 0xffff0000u;
      sum += lo.f * p.Wfc[(lane * 4 + cc) * 2] + hi.f * p.Wfc[(lane * 4 + cc) * 2 + 1];
    }
#pragma unroll
    for (int o = 32; o > 0; o >>= 1) sum += __shfl_down(sum, o, 64);
    if (lane == 0) p.out[row] = sigm(sum + p.bfc[0]);
  }
}

// ---------------- host launcher ----------------

extern "C" void kernel_launch(void* const* d_in, const int* in_sizes, int n_in,
                              void* d_out, int out_size, void* d_ws, size_t ws_size,
                              hipStream_t stream) {
  const int*   tokens = (const int*)d_in[0];
  const float* emb = (const float*)d_in[1];
  const float* W1  = (const float*)d_in[2];
  const float* U1  = (const float*)d_in[3];
  const float* b1  = (const float*)d_in[4];
  const float* W2  = (const float*)d_in[5];
  const float* U2  = (const float*)d_in[6];
  const float* b2  = (const float*)d_in[7];
  const float* Wfc = (const float*)d_in[8];
  const float* bfc = (const float*)d_in[9];

  char* ws = (char*)d_ws;
  size_t off = 0;
  auto alloc = [&](size_t bytes) {
    char* r = ws + off;
    off += (bytes + 255) & ~(size_t)255;
    return r;
  };
  __hip_bfloat16* Wz1t = (__hip_bfloat16*)alloc(2048UL * K1 * 2);
  __hip_bfloat16* Wz2t = (__hip_bfloat16*)alloc(2048UL * K2 * 2);
  float* bz1 = (float*)alloc(2048 * 4);
  float* bz2 = (float*)alloc(2048 * 4);
  __hip_bfloat16* Xall = (__hip_bfloat16*)alloc((size_t)TSTEPS * BATCH * EDIM * 2);
  // state: 24 h-slots (12 h1 + 12 h2) + flags (4096B), ALL zeroed in prep_gather
  const size_t state_bytes = 24UL * SLOT_BYTES + 4096;   // 12,593,152
  char* state = alloc(state_bytes);

  Params prm;
  prm.h1base = state;
  prm.h2base = state + 12UL * SLOT_BYTES;
  prm.flags  = (int*)(state + 24UL * SLOT_BYTES);

  prep_weights<<<dim3(14352), dim3(256), 0, stream>>>(W1, U1, b1, W2, U2, b2, Wz1t, Wz2t, bz1, bz2);
  prep_gather<<<dim3(10240), dim3(256), 0, stream>>>(tokens, emb, Xall,
                                                     (float4*)state, (int)(state_bytes / 16));

  hipFuncSetAttribute((const void*)lstm_seq,
                      hipFuncAttributeMaxDynamicSharedMemorySize, LDS_BYTES);

  prm.Wz1t = Wz1t; prm.Wz2t = Wz2t; prm.bz1 = bz1; prm.bz2 = bz2;
  prm.Xall = Xall;
  prm.Wfc = Wfc; prm.bfc = bfc;
  prm.out = (float*)d_out;

  lstm_seq<<<dim3(256), dim3(256), LDS_BYTES, stream>>>(prm);
}